// Round 9
// baseline (127.805 us; speedup 1.0000x reference)
//
#include <hip/hip_runtime.h>

// Problem constants (from reference setup_inputs)
#define BB 4
#define CC 12
#define DD 8
#define HG 16
#define WG 16
#define HH 1024
#define WW 1024

typedef float vf4 __attribute__((ext_vector_type(4)));
typedef _Float16 h8 __attribute__((ext_vector_type(8)));  // 16B LDS read unit

// Round-9: band-persistent software-pipelined blocks.
// Evidence: all pipes <40% busy, per-wave issue work ~2-4us but kernel 34us
// -> waves stalled in a phase-synchronized {burst loads -> barrier ->
// compute} schedule; memory idles during compute, ALUs idle during bursts.
// Fix: y-band (iy0,iy1) is constant across 64 rows, so stage the TWO RAW
// y-slices once (f16, y-interleaved) and stream 8 rows per block with
// register double-buffered prefetch of guide/image, applying the y-lerp
// in-register (wy0/wy1 are row-uniform).
//
// LDS layout: S[x*XSTRH + z*24 + c*2 + y] halfs.
//   XSTRH = 8z*24 + 16 pad = 208 halfs = 416 B (x-stride 104 quads ≡ 8 mod 32;
//   z contributes 12z quads mod 32 -> 8 distinct groups, guide-random z
//   spreads banks). Corner read base = x*416 + z*48 bytes, 16B-aligned ->
//   3x ds_read_b128 per (x,z) corner covering 12 channels x 2 y-slices.
#define XSTRH 208
#define RPB 8    // rows per block; 8 | 32 so a block never straddles an
                 // fy band (bands flip at h = 32 + 64k)
#define NSTG 12  // 2*16*8*12 = 3072 cells / 256 threads

__global__ __launch_bounds__(256) void slice_apply(
    const float* __restrict__ grid,   // [B,C,D,HG,WG]
    const float* __restrict__ guide,  // [B,H,W]
    const float* __restrict__ img,    // [B,3,H,W]
    float* __restrict__ out)          // [B,3,H,W]
{
    __shared__ _Float16 S[WG * XSTRH];  // 6656 B

    const int blk = blockIdx.x;
    const int b  = blk >> 7;                 // HH/RPB = 128 row-groups per batch
    const int h0 = (blk & 127) * RPB;

    // y-band shared by all RPB rows
    const float gy0 = (h0 + 0.5f) * ((float)HG / (float)HH);
    const float fy  = floorf(gy0 - 0.5f);
    const int   iy0 = max(0, min(HG - 1, (int)fy));
    const int   iy1 = max(0, min(HG - 1, (int)fy + 1));

    // ---- Issue the 12 staging loads first (L2/L3-resident grid).
    // j -> (x fastest for coalescing, then y, then z, then c).
    float sv[NSTG];
    int   sw[NSTG];
    #pragma unroll
    for (int t = 0; t < NSTG; ++t) {
        const int j = (int)threadIdx.x + t * 256;
        const int x    = j & 15;
        const int rest = j >> 4;          // 0..191
        const int y    = rest & 1;
        const int zc   = rest >> 1;       // 0..95
        const int z    = zc & 7;
        const int c    = zc >> 3;         // 0..11
        const int iy   = y ? iy1 : iy0;
        sv[t] = grid[((size_t)(b * CC + c) * DD + z) * (HG * WG) + iy * WG + x];
        sw[t] = x * XSTRH + z * 24 + c * 2 + y;
    }

    const int w0 = (int)threadIdx.x * 4;

    auto loadrow = [&](int r, vf4& G, vf4& I0, vf4& I1, vf4& I2) {
        const size_t pix = ((size_t)b * HH + (h0 + r)) * WW + w0;
        G = *reinterpret_cast<const vf4*>(guide + pix);
        const float* ib = img + (((size_t)b * 3) * HH + (h0 + r)) * WW + w0;
        I0 = __builtin_nontemporal_load(reinterpret_cast<const vf4*>(ib));
        I1 = __builtin_nontemporal_load(reinterpret_cast<const vf4*>(ib + (size_t)HH * WW));
        I2 = __builtin_nontemporal_load(reinterpret_cast<const vf4*>(ib + (size_t)2 * HH * WW));
    };

    // ---- Prefetch row 0's pixel data (in flight across the barrier).
    vf4 gA, a0A, a1A, a2A, gB, a0B, a1B, a2B;
    loadrow(0, gA, a0A, a1A, a2A);

    // ---- Convert + write slab (waits only on the 12 grid loads; the 4
    // pixel loads issued after them stay in flight).
    #pragma unroll
    for (int t = 0; t < NSTG; ++t) S[sw[t]] = (_Float16)sv[t];
    __syncthreads();

    // x cell pair is uniform across the 4 pixels of this thread
    const float scale = (float)WG / (float)WW;       // 1/64
    const float gx0 = (w0 + 0.5f) * scale;
    const float fx  = floorf(gx0 - 0.5f);
    const float tx0 = gx0 - 0.5f - fx;
    const int   ix0 = max(0, min(WG - 1, (int)fx));
    const int   ix1 = max(0, min(WG - 1, (int)fx + 1));
    const _Float16* Sx0 = S + ix0 * XSTRH;
    const _Float16* Sx1 = S + ix1 * XSTRH;

    auto compute = [&](int r, const vf4& G, const vf4& I0, const vf4& I1, const vf4& I2) {
        const int h = h0 + r;
        const float gy = (h + 0.5f) * ((float)HG / (float)HH);
        const float ty = gy - 0.5f - fy;     // row-uniform
        const float wy0 = 1.0f - ty, wy1 = ty;

        vf4 o0, o1, o2;
        #pragma unroll
        for (int p = 0; p < 4; ++p) {
            const float tx  = tx0 + (float)p * scale;
            const float wx0 = 1.0f - tx, wx1 = tx;

            const float gz  = G[p] * (float)DD;
            const float fz  = floorf(gz - 0.5f);
            const float tz  = gz - 0.5f - fz;
            const int   ifz = (int)fz;
            const int   iz0 = max(0, min(DD - 1, ifz));
            const int   iz1 = max(0, min(DD - 1, ifz + 1));
            const float wz0 = 1.0f - tz, wz1 = tz;

            float acc[12];
            #pragma unroll
            for (int k = 0; k < 12; ++k) acc[k] = 0.0f;

            // 3x ds_read_b128 per corner: 12 channels x (y0,y1) interleaved.
            // acc += (w*wy0)*v[2k] + (w*wy1)*v[2k+1] fuses to v_fma_mix_f32.
            auto accum = [&](const _Float16* P, float w) {
                const float wa = w * wy0, wb = w * wy1;
                const h8 v0 = *reinterpret_cast<const h8*>(P);       // ch 0..3
                const h8 v1 = *reinterpret_cast<const h8*>(P + 8);   // ch 4..7
                const h8 v2 = *reinterpret_cast<const h8*>(P + 16);  // ch 8..11
                #pragma unroll
                for (int k = 0; k < 4; ++k) {
                    acc[k]     += wa * (float)v0[2*k] + wb * (float)v0[2*k+1];
                    acc[4 + k] += wa * (float)v1[2*k] + wb * (float)v1[2*k+1];
                    acc[8 + k] += wa * (float)v2[2*k] + wb * (float)v2[2*k+1];
                }
            };
            accum(Sx0 + iz0 * 24, wz0 * wx0);
            accum(Sx1 + iz0 * 24, wz0 * wx1);
            accum(Sx0 + iz1 * 24, wz1 * wx0);
            accum(Sx1 + iz1 * 24, wz1 * wx1);

            const float im0 = I0[p], im1 = I1[p], im2 = I2[p];
            o0[p] = acc[0] * im0 + acc[1] * im1 + acc[2]  * im2 + acc[3];
            o1[p] = acc[4] * im0 + acc[5] * im1 + acc[6]  * im2 + acc[7];
            o2[p] = acc[8] * im0 + acc[9] * im1 + acc[10] * im2 + acc[11];
        }

        float* ob = out + (((size_t)b * 3) * HH + h) * WW + w0;
        *reinterpret_cast<vf4*>(ob) = o0;
        *reinterpret_cast<vf4*>(ob + (size_t)HH * WW) = o1;
        *reinterpret_cast<vf4*>(ob + (size_t)2 * HH * WW) = o2;
    };

    // ---- Software-pipelined row loop (static A/B register buffers,
    // unrolled by 2 so all indexing is compile-time — no scratch).
    #pragma unroll
    for (int r = 0; r < RPB; r += 2) {
        if (r + 1 < RPB) loadrow(r + 1, gB, a0B, a1B, a2B);
        compute(r, gA, a0A, a1A, a2A);
        if (r + 2 < RPB) loadrow(r + 2, gA, a0A, a1A, a2A);
        compute(r + 1, gB, a0B, a1B, a2B);
    }
}

extern "C" void kernel_launch(void* const* d_in, const int* in_sizes, int n_in,
                              void* d_out, int out_size, void* d_ws, size_t ws_size,
                              hipStream_t stream) {
    const float* grid  = (const float*)d_in[0];
    const float* guide = (const float*)d_in[1];
    const float* image = (const float*)d_in[2];
    float* out = (float*)d_out;

    const int nblocks = BB * HH / RPB;  // 512 blocks, 8 rows each
    slice_apply<<<nblocks, 256, 0, stream>>>(grid, guide, image, out);
}

// Round 10
// 118.951 us; speedup vs baseline: 1.0744x; 1.0744x over previous
//
#include <hip/hip_runtime.h>

// Problem constants (from reference setup_inputs)
#define BB 4
#define CC 12
#define DD 8
#define HG 16
#define WG 16
#define HH 1024
#define WW 1024

typedef float vf4 __attribute__((ext_vector_type(4)));
typedef _Float16 h4 __attribute__((ext_vector_type(4)));  // 8B LDS read unit
typedef _Float16 h2 __attribute__((ext_vector_type(2)));  // 4B LDS write unit

// Round-10: ROWS=1 lean blocks for NATURAL 6 waves/SIMD occupancy.
// Evidence chain: r9 (waves halved) regressed 10.5us -> latency-bound,
// TLP-starved. r4 (forced 6 waves on ~106-reg live set) collapsed the
// allocator (VGPR=40). r6 (cap at natural 4 waves) neutral. The untested
// cell: a kernel whose live set GENUINELY fits 6 waves/SIMD. Halving rows
// per block halves pixel state (4 vf4 = 16 regs) and staging fold; audited
// live set ~70-80 -> (256,6) is loose, no collapse expected.
//
// f16 slab, one row: S[x*XSTRH + z*12 + c] halfs, XSTRH = 96 data + 8 pad
// = 104 halfs = 208 B. Cells 24 B, 8B-aligned -> 3x ds_read_b64 per corner.
#define XSTRH 104
#define NSTG 3   // channel-PAIR staging: 768 pair-cells / 256 threads

__global__ __launch_bounds__(256, 6) void slice_apply(
    const float* __restrict__ grid,   // [B,C,D,HG,WG]
    const float* __restrict__ guide,  // [B,H,W]
    const float* __restrict__ img,    // [B,3,H,W]
    float* __restrict__ out)          // [B,3,H,W]
{
    __shared__ _Float16 S[WG * XSTRH];  // 3328 B

    const int blk = blockIdx.x;
    const int b = blk >> 10;               // HH rows per batch
    const int h = blk & 1023;

    // y-cell pair for this row
    const float gy = (h + 0.5f) * ((float)HG / (float)HH);
    const float fy = floorf(gy - 0.5f);
    const float ty = gy - 0.5f - fy;
    const int   iy0 = max(0, min(HG - 1, (int)fy));
    const int   iy1 = max(0, min(HG - 1, (int)fy + 1));

    // ---- Issue the block's 12 grid loads first (channel-pair layout;
    // consecutive threads read consecutive x -> coalesced; L1/L2-resident).
    float a0[NSTG], a1[NSTG], c0v[NSTG], c1v[NSTG];
    int   so[NSTG];
    #pragma unroll
    for (int t = 0; t < NSTG; ++t) {
        const int j = (int)threadIdx.x + t * 256;
        const int x = j & 15;
        const int z = (j >> 4) & 7;
        const int pr = j >> 7;              // 0..5
        const size_t base0 = ((size_t)(b * CC + 2 * pr) * DD + z) * (HG * WG);
        const size_t base1 = ((size_t)(b * CC + 2 * pr + 1) * DD + z) * (HG * WG);
        a0[t] = grid[base0 + iy0 * WG + x];
        a1[t] = grid[base0 + iy1 * WG + x];
        c0v[t] = grid[base1 + iy0 * WG + x];
        c1v[t] = grid[base1 + iy1 * WG + x];
        so[t] = x * XSTRH + z * 12 + 2 * pr;
    }

    // ---- Issue the 4 guide/image vector loads BEFORE the barrier (the
    // barrier fence stops the compiler hoisting them itself). Latency
    // drains under the staging fold + barrier wait.
    const int w0 = (int)threadIdx.x * 4;
    const size_t pix = ((size_t)b * HH + h) * WW + w0;
    const vf4 g4 = *reinterpret_cast<const vf4*>(guide + pix);
    const float* ib = img + (((size_t)b * 3) * HH + h) * WW + w0;
    const vf4 i0 = __builtin_nontemporal_load(reinterpret_cast<const vf4*>(ib));
    const vf4 i1 = __builtin_nontemporal_load(reinterpret_cast<const vf4*>(ib + (size_t)HH * WW));
    const vf4 i2 = __builtin_nontemporal_load(reinterpret_cast<const vf4*>(ib + (size_t)2 * HH * WW));

    // ---- Fold the y-lerp in f32, convert once (RTN), one ds_write_b32
    // per channel-pair.
    #pragma unroll
    for (int t = 0; t < NSTG; ++t) {
        const float f0 = a0[t] + ty * (a1[t] - a0[t]);
        const float f1 = c0v[t] + ty * (c1v[t] - c0v[t]);
        h2 v; v[0] = (_Float16)f0; v[1] = (_Float16)f1;
        *reinterpret_cast<h2*>(&S[so[t]]) = v;
    }
    __syncthreads();

    // x cell pair is uniform across the 4 pixels of this thread
    const float scale = (float)WG / (float)WW;       // 1/64
    const float gx0 = (w0 + 0.5f) * scale;
    const float fx  = floorf(gx0 - 0.5f);
    const float tx0 = gx0 - 0.5f - fx;
    const int   ix0 = max(0, min(WG - 1, (int)fx));
    const int   ix1 = max(0, min(WG - 1, (int)fx + 1));
    const _Float16* Sx0 = S + ix0 * XSTRH;
    const _Float16* Sx1 = S + ix1 * XSTRH;

    vf4 o0, o1, o2;

    #pragma unroll
    for (int p = 0; p < 4; ++p) {
        const float tx  = tx0 + (float)p * scale;
        const float wx0 = 1.0f - tx, wx1 = tx;

        const float gz  = g4[p] * (float)DD;
        const float fz  = floorf(gz - 0.5f);
        const float tz  = gz - 0.5f - fz;
        const int   ifz = (int)fz;
        const int   iz0 = max(0, min(DD - 1, ifz));
        const int   iz1 = max(0, min(DD - 1, ifz + 1));
        const float wz0 = 1.0f - tz, wz1 = tz;

        const float w00 = wz0 * wx0, w01 = wz0 * wx1;
        const float w10 = wz1 * wx0, w11 = wz1 * wx1;

        float acc[12];
        #pragma unroll
        for (int k = 0; k < 12; ++k) acc[k] = 0.0f;

        // 3x ds_read_b64 per corner; (float)h * w + acc fuses to
        // v_fma_mix_f32.
        auto accum = [&](const _Float16* P, float w) {
            const h4 a = *reinterpret_cast<const h4*>(P);
            const h4 e = *reinterpret_cast<const h4*>(P + 4);
            const h4 f = *reinterpret_cast<const h4*>(P + 8);
            #pragma unroll
            for (int k = 0; k < 4; ++k) {
                acc[k]     += w * (float)a[k];
                acc[4 + k] += w * (float)e[k];
                acc[8 + k] += w * (float)f[k];
            }
        };
        accum(Sx0 + iz0 * 12, w00);
        accum(Sx1 + iz0 * 12, w01);
        accum(Sx0 + iz1 * 12, w10);
        accum(Sx1 + iz1 * 12, w11);

        const float im0 = i0[p], im1 = i1[p], im2 = i2[p];
        o0[p] = acc[0] * im0 + acc[1] * im1 + acc[2]  * im2 + acc[3];
        o1[p] = acc[4] * im0 + acc[5] * im1 + acc[6]  * im2 + acc[7];
        o2[p] = acc[8] * im0 + acc[9] * im1 + acc[10] * im2 + acc[11];
    }

    // Plain stores (r8 win): write-back L2, no NT bypass.
    float* ob = out + (((size_t)b * 3) * HH + h) * WW + w0;
    *reinterpret_cast<vf4*>(ob) = o0;
    *reinterpret_cast<vf4*>(ob + (size_t)HH * WW) = o1;
    *reinterpret_cast<vf4*>(ob + (size_t)2 * HH * WW) = o2;
}

extern "C" void kernel_launch(void* const* d_in, const int* in_sizes, int n_in,
                              void* d_out, int out_size, void* d_ws, size_t ws_size,
                              hipStream_t stream) {
    const float* grid  = (const float*)d_in[0];
    const float* guide = (const float*)d_in[1];
    const float* image = (const float*)d_in[2];
    float* out = (float*)d_out;

    const int nblocks = BB * HH;  // 4096 blocks, 1 row each
    slice_apply<<<nblocks, 256, 0, stream>>>(grid, guide, image, out);
}

// Round 11
// 118.589 us; speedup vs baseline: 1.0777x; 1.0030x over previous
//
#include <hip/hip_runtime.h>

// Problem constants (from reference setup_inputs)
#define BB 4
#define CC 12
#define DD 8
#define HG 16
#define WG 16
#define HH 1024
#define WW 1024

typedef float vf4 __attribute__((ext_vector_type(4)));
typedef _Float16 h4 __attribute__((ext_vector_type(4)));  // 8B LDS read unit
typedef _Float16 h2 __attribute__((ext_vector_type(2)));  // 4B LDS write unit

// Round-11: cross-chunk software pipeline at r8's occupancy.
// Ledger: waves 8/16/24 per CU -> bad/base/neutral (r9/r8/r10): occupancy
// exonerated. LDS halved -> null (r7). Only real wins were load/store
// overlap (r5 hoist, r8 plain stores). Remaining cell: keep loads in
// flight DURING compute. Block = 4 rows as 2 chunks of 2; chunk1's pixel
// loads issue right after the first barrier, so compute0 always has 8
// vmem in flight. Staging regs (12) fold chunk1's slabs with no new
// global traffic. Peak live ~110 regs under the 128 cap (r1's thrash came
// from 64 pixel regs + cap; here chunk0's 32 die as chunk1's 32 arrive).
//
// f16 slab per row: S[r][x*XSTRH + z*12 + c] halfs, XSTRH = 96 data + 8
// pad = 104 halfs = 208 B. Cells 24 B, 8B-aligned -> 3x ds_read_b64.
#define XSTRH 104
#define ROWSB 4  // rows per block (2 chunks x 2 rows); 4-aligned groups
                 // never straddle an fy band (bands flip at h = 32 + 64k)
#define NSTG 3   // channel-PAIR staging: 768 pair-cells / 256 threads

__global__ __launch_bounds__(256, 4) void slice_apply(
    const float* __restrict__ grid,   // [B,C,D,HG,WG]
    const float* __restrict__ guide,  // [B,H,W]
    const float* __restrict__ img,    // [B,3,H,W]
    float* __restrict__ out)          // [B,3,H,W]
{
    __shared__ _Float16 S[ROWSB * WG * XSTRH];  // 4 slabs, 13312 B

    const int blk = blockIdx.x;
    const int b  = blk >> 8;                 // HH/ROWSB = 256 groups per batch
    const int h0 = (blk & 255) * ROWSB;

    // y-band shared by all 4 rows
    const float gy0 = (h0 + 0.5f) * ((float)HG / (float)HH);
    const float fy  = floorf(gy0 - 0.5f);
    const int   iy0 = max(0, min(HG - 1, (int)fy));
    const int   iy1 = max(0, min(HG - 1, (int)fy + 1));

    float tyr[ROWSB];
    #pragma unroll
    for (int r = 0; r < ROWSB; ++r) {
        const float gy = (h0 + r + 0.5f) * ((float)HG / (float)HH);
        tyr[r] = gy - 0.5f - fy;            // ty in [0,1)
    }

    // ---- 12 grid loads into registers (channel-pair layout; coalesced;
    // L1/L2-resident). Held across both chunks' folds.
    float a0[NSTG], a1[NSTG], c0v[NSTG], c1v[NSTG];
    int   so[NSTG];
    #pragma unroll
    for (int t = 0; t < NSTG; ++t) {
        const int j = (int)threadIdx.x + t * 256;
        const int x = j & 15;
        const int z = (j >> 4) & 7;
        const int pr = j >> 7;              // 0..5
        const size_t base0 = ((size_t)(b * CC + 2 * pr) * DD + z) * (HG * WG);
        const size_t base1 = ((size_t)(b * CC + 2 * pr + 1) * DD + z) * (HG * WG);
        a0[t] = grid[base0 + iy0 * WG + x];
        a1[t] = grid[base0 + iy1 * WG + x];
        c0v[t] = grid[base1 + iy0 * WG + x];
        c1v[t] = grid[base1 + iy1 * WG + x];
        so[t] = x * XSTRH + z * 12 + 2 * pr;
    }

    const int w0 = (int)threadIdx.x * 4;

    auto loadrow = [&](int r, vf4& G, vf4& I0, vf4& I1, vf4& I2) {
        const size_t pix = ((size_t)b * HH + (h0 + r)) * WW + w0;
        G = *reinterpret_cast<const vf4*>(guide + pix);
        const float* ib = img + (((size_t)b * 3) * HH + (h0 + r)) * WW + w0;
        I0 = __builtin_nontemporal_load(reinterpret_cast<const vf4*>(ib));
        I1 = __builtin_nontemporal_load(reinterpret_cast<const vf4*>(ib + (size_t)HH * WW));
        I2 = __builtin_nontemporal_load(reinterpret_cast<const vf4*>(ib + (size_t)2 * HH * WW));
    };

    auto fold2 = [&](int r0) {   // fold rows r0, r0+1 into slabs r0, r0+1
        #pragma unroll
        for (int t = 0; t < NSTG; ++t) {
            const float d0 = a1[t] - a0[t];
            const float d1 = c1v[t] - c0v[t];
            #pragma unroll
            for (int rr = 0; rr < 2; ++rr) {
                const float ty = tyr[r0 + rr];
                h2 v;
                v[0] = (_Float16)(a0[t] + ty * d0);
                v[1] = (_Float16)(c0v[t] + ty * d1);
                *reinterpret_cast<h2*>(&S[(r0 + rr) * (WG * XSTRH) + so[t]]) = v;
            }
        }
    };

    // ---- Chunk 0 pixel loads (issued before the fold so they're in
    // flight across the barrier — r5's proven hoist).
    vf4 gA0, iA00, iA01, iA02, gA1, iA10, iA11, iA12;
    loadrow(0, gA0, iA00, iA01, iA02);
    loadrow(1, gA1, iA10, iA11, iA12);

    fold2(0);
    __syncthreads();

    // x cell pair is uniform across the 4 pixels of this thread
    const float scale = (float)WG / (float)WW;       // 1/64
    const float gx0 = (w0 + 0.5f) * scale;
    const float fx  = floorf(gx0 - 0.5f);
    const float tx0 = gx0 - 0.5f - fx;
    const int   ix0 = max(0, min(WG - 1, (int)fx));
    const int   ix1 = max(0, min(WG - 1, (int)fx + 1));

    auto computerow = [&](int r, const vf4& G, const vf4& I0, const vf4& I1, const vf4& I2) {
        const _Float16* Sr  = S + r * (WG * XSTRH);
        const _Float16* Sx0 = Sr + ix0 * XSTRH;
        const _Float16* Sx1 = Sr + ix1 * XSTRH;

        vf4 o0, o1, o2;
        #pragma unroll
        for (int p = 0; p < 4; ++p) {
            const float tx  = tx0 + (float)p * scale;
            const float wx0 = 1.0f - tx, wx1 = tx;

            const float gz  = G[p] * (float)DD;
            const float fz  = floorf(gz - 0.5f);
            const float tz  = gz - 0.5f - fz;
            const int   ifz = (int)fz;
            const int   iz0 = max(0, min(DD - 1, ifz));
            const int   iz1 = max(0, min(DD - 1, ifz + 1));
            const float wz0 = 1.0f - tz, wz1 = tz;

            const float w00 = wz0 * wx0, w01 = wz0 * wx1;
            const float w10 = wz1 * wx0, w11 = wz1 * wx1;

            float acc[12];
            #pragma unroll
            for (int k = 0; k < 12; ++k) acc[k] = 0.0f;

            auto accum = [&](const _Float16* P, float w) {
                const h4 a = *reinterpret_cast<const h4*>(P);
                const h4 e = *reinterpret_cast<const h4*>(P + 4);
                const h4 f = *reinterpret_cast<const h4*>(P + 8);
                #pragma unroll
                for (int k = 0; k < 4; ++k) {
                    acc[k]     += w * (float)a[k];
                    acc[4 + k] += w * (float)e[k];
                    acc[8 + k] += w * (float)f[k];
                }
            };
            accum(Sx0 + iz0 * 12, w00);
            accum(Sx1 + iz0 * 12, w01);
            accum(Sx0 + iz1 * 12, w10);
            accum(Sx1 + iz1 * 12, w11);

            const float im0 = I0[p], im1 = I1[p], im2 = I2[p];
            o0[p] = acc[0] * im0 + acc[1] * im1 + acc[2]  * im2 + acc[3];
            o1[p] = acc[4] * im0 + acc[5] * im1 + acc[6]  * im2 + acc[7];
            o2[p] = acc[8] * im0 + acc[9] * im1 + acc[10] * im2 + acc[11];
        }

        // Plain stores (r8 win): write-back L2, no NT bypass.
        float* ob = out + (((size_t)b * 3) * HH + (h0 + r)) * WW + w0;
        *reinterpret_cast<vf4*>(ob) = o0;
        *reinterpret_cast<vf4*>(ob + (size_t)HH * WW) = o1;
        *reinterpret_cast<vf4*>(ob + (size_t)2 * HH * WW) = o2;
    };

    // ---- Chunk 1 pixel loads issue FIRST after the barrier, so they are
    // in flight throughout chunk 0's compute (the pipeline's whole point).
    vf4 gB0, iB00, iB01, iB02, gB1, iB10, iB11, iB12;
    loadrow(2, gB0, iB00, iB01, iB02);
    loadrow(3, gB1, iB10, iB11, iB12);

    computerow(0, gA0, iA00, iA01, iA02);
    computerow(1, gA1, iA10, iA11, iA12);

    // Fold chunk 1 (slabs 2,3) — register-only inputs, ds_write to slabs
    // nobody is reading; single barrier publishes before compute.
    fold2(2);
    __syncthreads();

    computerow(2, gB0, iB00, iB01, iB02);
    computerow(3, gB1, iB10, iB11, iB12);
}

extern "C" void kernel_launch(void* const* d_in, const int* in_sizes, int n_in,
                              void* d_out, int out_size, void* d_ws, size_t ws_size,
                              hipStream_t stream) {
    const float* grid  = (const float*)d_in[0];
    const float* guide = (const float*)d_in[1];
    const float* image = (const float*)d_in[2];
    float* out = (float*)d_out;

    const int nblocks = BB * HH / ROWSB;  // 1024 blocks, 4 rows each
    slice_apply<<<nblocks, 256, 0, stream>>>(grid, guide, image, out);
}

// Round 12
// 118.122 us; speedup vs baseline: 1.0820x; 1.0040x over previous
//
#include <hip/hip_runtime.h>

// Problem constants (from reference setup_inputs)
#define BB 4
#define CC 12
#define DD 8
#define HG 16
#define WG 16
#define HH 1024
#define WW 1024

// Native 4-float vector (clang ext vector).
typedef float vf4 __attribute__((ext_vector_type(4)));
typedef _Float16 h4 __attribute__((ext_vector_type(4)));  // 8B LDS read unit
typedef _Float16 h2 __attribute__((ext_vector_type(2)));  // 4B LDS write unit

// FINAL (r8 restore — best measured: 117.3 us).
// Session ledger: occupancy 8/16/24 waves/CU -> bad/base/null; LDS
// traffic halved (f16) -> null; chunked + persistent pipelining -> null;
// forced VGPR caps -> collapse or null. Kept wins: load hoist above the
// barrier (r5, -4us) and plain write-back stores instead of NT (r8,
// -2.4us). Kernel ~28us vs 18.6us ideal at copy-BW; remainder is a
// latency equilibrium no source-level lever dented (all pipes <40%).
//
// f16 slab layout per row: S[x*XSTRH + z*12 + c] (halfs), XSTRH = 96 data
// + 8 pad = 104 halfs = 208 B. Cells are 24 B, 8B-aligned -> 3x ds_read_b64.
#define XSTRH 104
#define ROWS 2   // grid = 2048 blocks. Even h0 never straddles an fy band.
#define NSTG 3   // channel-PAIR staging stages: 768 pair-cells / 256 threads

__global__ __launch_bounds__(256, 4) void slice_apply(
    const float* __restrict__ grid,   // [B,C,D,HG,WG]
    const float* __restrict__ guide,  // [B,H,W]
    const float* __restrict__ img,    // [B,3,H,W]
    float* __restrict__ out)          // [B,3,H,W]
{
    __shared__ _Float16 S[ROWS * WG * XSTRH];  // 6656 B

    const int blk = blockIdx.x;
    const int b  = blk >> 9;                 // HH/ROWS = 512 row-groups per batch
    const int h0 = (blk & 511) * ROWS;

    // y-cell pair shared by all ROWS rows of this block
    const float gy0 = (h0 + 0.5f) * ((float)HG / (float)HH);
    const float fy  = floorf(gy0 - 0.5f);
    const int   iy0 = max(0, min(HG - 1, (int)fy));
    const int   iy1 = max(0, min(HG - 1, (int)fy + 1));

    float wy1r[ROWS];
    #pragma unroll
    for (int r = 0; r < ROWS; ++r) {
        const float gy = (h0 + r + 0.5f) * ((float)HG / (float)HH);
        wy1r[r] = gy - 0.5f - fy;           // ty in [0,1)
    }

    // ---- Issue the block's 12 grid loads first (channel-pair layout).
    float a0[NSTG], a1[NSTG], c0v[NSTG], c1v[NSTG];
    int   so[NSTG];
    #pragma unroll
    for (int t = 0; t < NSTG; ++t) {
        const int j = (int)threadIdx.x + t * 256;
        const int x = j & 15;
        const int z = (j >> 4) & 7;
        const int pr = j >> 7;              // 0..5
        const size_t base0 = ((size_t)(b * CC + 2 * pr) * DD + z) * (HG * WG);
        const size_t base1 = ((size_t)(b * CC + 2 * pr + 1) * DD + z) * (HG * WG);
        a0[t] = grid[base0 + iy0 * WG + x];
        a1[t] = grid[base0 + iy1 * WG + x];
        c0v[t] = grid[base1 + iy0 * WG + x];
        c1v[t] = grid[base1 + iy1 * WG + x];
        so[t] = x * XSTRH + z * 12 + 2 * pr;
    }

    // ---- Issue all 8 guide/image vector loads BEFORE the barrier (the
    // barrier fence stops the compiler hoisting them itself).
    const int w0 = (int)threadIdx.x * 4;
    vf4 g4[ROWS], i0[ROWS], i1[ROWS], i2[ROWS];
    #pragma unroll
    for (int r = 0; r < ROWS; ++r) {
        const size_t pix = ((size_t)b * HH + (h0 + r)) * WW + w0;
        g4[r] = *reinterpret_cast<const vf4*>(guide + pix);
        const float* ib = img + (((size_t)b * 3) * HH + (h0 + r)) * WW + w0;
        i0[r] = __builtin_nontemporal_load(reinterpret_cast<const vf4*>(ib));
        i1[r] = __builtin_nontemporal_load(reinterpret_cast<const vf4*>(ib + (size_t)HH * WW));
        i2[r] = __builtin_nontemporal_load(reinterpret_cast<const vf4*>(ib + (size_t)2 * HH * WW));
    }

    // ---- Fold the y-lerp in f32, convert once (RTN), store channel-pairs
    // as one ds_write_b32 each.
    #pragma unroll
    for (int t = 0; t < NSTG; ++t) {
        const float d0 = a1[t] - a0[t];
        const float d1 = c1v[t] - c0v[t];
        #pragma unroll
        for (int r = 0; r < ROWS; ++r) {
            const float f0 = a0[t] + wy1r[r] * d0;
            const float f1 = c0v[t] + wy1r[r] * d1;
            h2 v; v[0] = (_Float16)f0; v[1] = (_Float16)f1;
            *reinterpret_cast<h2*>(&S[r * (WG * XSTRH) + so[t]]) = v;
        }
    }
    __syncthreads();

    // x cell pair is uniform across the 4 pixels of this thread
    const float scale = (float)WG / (float)WW;       // 1/64
    const float gx0 = (w0 + 0.5f) * scale;
    const float fx  = floorf(gx0 - 0.5f);
    const float tx0 = gx0 - 0.5f - fx;
    const int   ix0 = max(0, min(WG - 1, (int)fx));
    const int   ix1 = max(0, min(WG - 1, (int)fx + 1));

    #pragma unroll
    for (int r = 0; r < ROWS; ++r) {
        const int h = h0 + r;
        const _Float16* Sr  = S + r * (WG * XSTRH);
        const _Float16* Sx0 = Sr + ix0 * XSTRH;
        const _Float16* Sx1 = Sr + ix1 * XSTRH;

        vf4 o0, o1, o2;

        #pragma unroll
        for (int p = 0; p < 4; ++p) {
            const float tx  = tx0 + (float)p * scale;
            const float wx0 = 1.0f - tx, wx1 = tx;

            const float gv = g4[r][p];
            const float gz  = gv * (float)DD;
            const float fz  = floorf(gz - 0.5f);
            const float tz  = gz - 0.5f - fz;
            const int   iz0 = max(0, min(DD - 1, (int)fz));
            const int   iz1 = max(0, min(DD - 1, (int)fz + 1));
            const float wz0 = 1.0f - tz, wz1 = tz;

            const float w00 = wz0 * wx0, w01 = wz0 * wx1;
            const float w10 = wz1 * wx0, w11 = wz1 * wx1;

            float acc[12];
            #pragma unroll
            for (int k = 0; k < 12; ++k) acc[k] = 0.0f;

            // 3x ds_read_b64 per cell; (float)h * w + acc fuses to
            // v_fma_mix_f32.
            auto accum = [&](const _Float16* P, float w) {
                const h4 a = *reinterpret_cast<const h4*>(P);
                const h4 e = *reinterpret_cast<const h4*>(P + 4);
                const h4 f = *reinterpret_cast<const h4*>(P + 8);
                #pragma unroll
                for (int k = 0; k < 4; ++k) {
                    acc[k]     += w * (float)a[k];
                    acc[4 + k] += w * (float)e[k];
                    acc[8 + k] += w * (float)f[k];
                }
            };
            accum(Sx0 + iz0 * 12, w00);
            accum(Sx1 + iz0 * 12, w01);
            accum(Sx0 + iz1 * 12, w10);
            accum(Sx1 + iz1 * 12, w11);

            const float im0 = i0[r][p];
            const float im1 = i1[r][p];
            const float im2 = i2[r][p];

            o0[p] = acc[0] * im0 + acc[1] * im1 + acc[2]  * im2 + acc[3];
            o1[p] = acc[4] * im0 + acc[5] * im1 + acc[6]  * im2 + acc[7];
            o2[p] = acc[8] * im0 + acc[9] * im1 + acc[10] * im2 + acc[11];
        }

        // Plain stores (r8 win): route writes through the write-back L2.
        float* ob = out + (((size_t)b * 3) * HH + h) * WW + w0;
        *reinterpret_cast<vf4*>(ob) = o0;
        *reinterpret_cast<vf4*>(ob + (size_t)HH * WW) = o1;
        *reinterpret_cast<vf4*>(ob + (size_t)2 * HH * WW) = o2;
    }
}

extern "C" void kernel_launch(void* const* d_in, const int* in_sizes, int n_in,
                              void* d_out, int out_size, void* d_ws, size_t ws_size,
                              hipStream_t stream) {
    const float* grid  = (const float*)d_in[0];
    const float* guide = (const float*)d_in[1];
    const float* image = (const float*)d_in[2];
    float* out = (float*)d_out;

    const int nblocks = BB * HH / ROWS;  // 2048 blocks, 2 rows each
    slice_apply<<<nblocks, 256, 0, stream>>>(grid, guide, image, out);
}